// Round 10
// baseline (302.482 us; speedup 1.0000x reference)
//
#include <hip/hip_runtime.h>
#include <hip/hip_bf16.h>

typedef unsigned short u16;
typedef unsigned char  u8;
typedef unsigned int   u32;
typedef __attribute__((ext_vector_type(8))) short  short8;
typedef __attribute__((ext_vector_type(8))) __bf16 bf16x8;
typedef __attribute__((ext_vector_type(4))) float  f32x4;
typedef __attribute__((ext_vector_type(4))) int    i32x4;

#define DI static __device__ __forceinline__

constexpr int T_ = 4, B_ = 64, C_ = 384, N_ = 196, NH_ = 8, DH_ = 48;
constexpr int J1_ = B_ * N_;           // 12544 columns per t-slice (= 98*128)
constexpr int J_  = T_ * J1_;          // 50176 flat columns
constexpr int K2_ = 2 * C_;            // 768 (hi|lo split-K)
constexpr int M1_ = 3 * C_;            // 1152 (q|k|v output channels)

DI u16 f2bf(float x){ __hip_bfloat16 h = __float2bfloat16(x); u16 u; __builtin_memcpy(&u,&h,2); return u; }
DI float bf2f(u16 u){ __hip_bfloat16 h; __builtin_memcpy(&h,&u,2); return __bfloat162float(h); }

DI void gload16(const void* g, void* lds){
  __builtin_amdgcn_global_load_lds((const __attribute__((address_space(1))) u32*)g,
                                   (__attribute__((address_space(3))) u32*)lds, 16, 0, 0);
}
DI bf16x8 ldbf8(const u16* p){ short8 v = *(const short8*)p; return __builtin_bit_cast(bf16x8, v); }
DI int SWZ(int n){ return ((n >> 3) ^ (n >> 5)) & 3; }

// ---------------------------------------------------------------- K0: prep
// Weights in fragment-major coalesced layout (one 16B/lane load per fragment):
// A2f[bm][kt][wm][mt][ks2][lane][8]; cc = bm*128+wm*64+mt*16+(lane&15);
// k = kt*64+ks2*32+(lane>>4)*8+e (k<384: bf16 hi; else exact lo residual).
__global__ __launch_bounds__(256) void k0_prep(
    const float* __restrict__ qw, const float* __restrict__ kw,
    const float* __restrict__ vw, const float* __restrict__ pw,
    const float* __restrict__ qbn, const float* __restrict__ kbn,
    const float* __restrict__ vbn, const float* __restrict__ pbn,
    u16* __restrict__ A2f, u16* __restrict__ A2pf,
    float* __restrict__ invq, float* __restrict__ betaq,
    float* __restrict__ invp, float* __restrict__ betap)
{
  int id = blockIdx.x * 256 + threadIdx.x;
  const int nAf = M1_ * K2_;   // 884736
  const int nPf = C_ * K2_;    // 294912
  if (id < nAf) {
    int tmp = id;
    int e    = tmp & 7;  tmp >>= 3;
    int lane = tmp & 63; tmp >>= 6;
    int ks2  = tmp & 1;  tmp >>= 1;
    int mt   = tmp & 3;  tmp >>= 2;
    int wm   = tmp & 1;  tmp >>= 1;
    int kt   = tmp % 12;
    int bm   = tmp / 12;
    int cc = bm*128 + wm*64 + mt*16 + (lane & 15);
    int k  = kt*64 + ks2*32 + (lane >> 4)*8 + e;
    int br = cc / C_, row = cc % C_;
    const float* w = (br == 0) ? qw : ((br == 1) ? kw : vw);
    float wv = w[row * C_ + (k < C_ ? k : k - C_)];
    u16 hi = f2bf(wv);
    A2f[id] = (k < C_) ? hi : f2bf(__fsub_rn(wv, bf2f(hi)));
  } else if (id < nAf + nPf) {
    int tmp = id - nAf;
    int id2 = tmp;
    int e    = tmp & 7;  tmp >>= 3;
    int lane = tmp & 63; tmp >>= 6;
    int ks2  = tmp & 1;  tmp >>= 1;
    int mt   = tmp & 3;  tmp >>= 2;
    int wm   = tmp & 1;  tmp >>= 1;
    int kt   = tmp % 12;
    int bm   = tmp / 12;
    int cc = bm*128 + wm*64 + mt*16 + (lane & 15);
    int k  = kt*64 + ks2*32 + (lane >> 4)*8 + e;
    float wv = pw[cc * C_ + (k < C_ ? k : k - C_)];
    u16 hi = f2bf(wv);
    A2pf[id2] = (k < C_) ? hi : f2bf(__fsub_rn(wv, bf2f(hi)));
  } else if (id < nAf + nPf + M1_) {
    int c = id - nAf - nPf;
    int br = c / C_, cr = c % C_;
    const float* p = (br == 0) ? qbn : ((br == 1) ? kbn : vbn);
    float g = p[cr], bb = p[C_ + cr], mm = p[2*C_ + cr], vv = p[3*C_ + cr];
    float inv = g / sqrtf(__fadd_rn(vv, 1e-5f));
    invq[c] = inv; betaq[c] = __fsub_rn(bb, __fmul_rn(mm, inv));
  } else if (id < nAf + nPf + M1_ + C_) {
    int c = id - nAf - nPf - M1_;
    float g = pbn[c], bb = pbn[C_ + c], mm = pbn[2*C_ + c], vv = pbn[3*C_ + c];
    float inv = g / sqrtf(__fadd_rn(vv, 1e-5f));
    invp[c] = inv; betap[c] = __fsub_rn(bb, __fmul_rn(mm, inv));
  }
}

// ---------------------------------------------------------------- K1: LIF(x) -> xs_t[j][c]
__global__ __launch_bounds__(256) void k1_lif_x(const float* __restrict__ x, u16* __restrict__ xs_t)
{
  int b = blockIdx.x / 12, ch = blockIdx.x % 12;
  int c0 = ch * 32;
  __shared__ u16 sp[4 * 32 * 198];
  int tid = threadIdx.x;
  for (int idx = tid; idx < 32 * N_; idx += 256) {
    int ci = idx / N_, n = idx % N_;
    float v = 0.f;
    for (int t = 0; t < 4; t++) {
      float xv = x[((size_t)((t*B_ + b)*C_ + c0 + ci))*N_ + n];
      v = __fadd_rn(v, __fmul_rn(__fsub_rn(xv, v), 0.5f));
      bool s = (v >= 1.0f);
      sp[(t*32 + ci)*198 + n] = s ? (u16)0x3F80 : (u16)0;
      v = __fmul_rn(v, s ? 0.f : 1.f);
    }
  }
  __syncthreads();
  for (int idx = tid; idx < 4 * 32 * N_; idx += 256) {
    int ci = idx & 31; int q = idx >> 5; int n = q % N_; int t = q / N_;
    xs_t[((size_t)((t*B_ + b)*N_ + n))*C_ + c0 + ci] = sp[(t*32 + ci)*198 + n];
  }
}

// ---------------------------------------------------------------- G1: branch GEMM
// 2-phase double-buffered B (2x16 KB), single barrier per K-step with counted
// vmcnt(8): stage of tile u+1 drains AFTER tile u's MFMA phase; A fragments
// from L2-hot fragment-major table, prefetched one step ahead (WAR-ordered).
__global__ __launch_bounds__(256, 2) void g1_branch(
    const u16* __restrict__ A2f, const u16* __restrict__ xs_t,
    const float* __restrict__ invq, const float* __restrict__ betaq,
    u8* __restrict__ qs, u8* __restrict__ ks_, u8* __restrict__ vs)
{
  int blk = blockIdx.x;
  int grp = blk / 72, rem = blk % 72;
  int bm = rem >> 3;
  int jt = grp * 8 + (rem & 7);
  if (jt >= 98) return;
  int cc0 = bm * 128;
  int colb = jt * 128;

  __shared__ u16 Bt[2][128 * 64];

  int tid = threadIdx.x;
  int lane = tid & 63, w = tid >> 6;
  int lr = lane & 15, lg = lane >> 4;
  int rsw = lr & 7;
  int wm = w & 1;
  int mrow = wm * 64, ncol = (w >> 1) * 64;

  float vst[4][4][4];
  #pragma unroll
  for (int a = 0; a < 4; a++)
    #pragma unroll
    for (int bq = 0; bq < 4; bq++)
      #pragma unroll
      for (int r = 0; r < 4; r++) vst[a][bq][r] = 0.f;

  f32x4 acc[4][4];
  bf16x8 af[2][4];

  auto STAGE = [&](int bi, int u2) {
    int t2 = u2 / 12, kt2 = u2 % 12;
    long j0 = (long)t2 * J1_ + colb;
    int ck0 = kt2 * 64;
    int ckB = (ck0 >= C_) ? (ck0 - C_) : ck0;
    #pragma unroll
    for (int i = 0; i < 4; i++) {
      int L0 = tid + i * 256;            // 0..1023
      int r = L0 >> 3;
      int c = (L0 & 7) ^ (r & 7);        // inverse-swizzled source chunk
      gload16(xs_t + (size_t)(j0 + r) * C_ + ckB + c * 8, &Bt[bi][L0 * 8]);
    }
  };

  auto LOADA = [&](int kt2) {
    int wb = (bm * 12 + kt2) * 2 + wm;
    #pragma unroll
    for (int ks2 = 0; ks2 < 2; ks2++)
      #pragma unroll
      for (int mt = 0; mt < 4; mt++)
        af[ks2][mt] = ldbf8(A2f + ((size_t)(((wb * 4 + mt) * 2 + ks2) * 64) + lane) * 8);
  };

  STAGE(0, 0);
  LOADA(0);
  asm volatile("s_waitcnt vmcnt(0)" ::: "memory");
  __builtin_amdgcn_s_barrier();

  for (int u = 0; u < 48; u++) {
    int t = u / 12, kt = u - t * 12;
    int cur = u & 1;

    if (u + 1 < 48) STAGE(cur ^ 1, u + 1);   // write OTHER buffer (safe: its readers retired last step)

    if (kt == 0) {
      #pragma unroll
      for (int a = 0; a < 4; a++)
        #pragma unroll
        for (int bq = 0; bq < 4; bq++) acc[a][bq] = (f32x4){0.f, 0.f, 0.f, 0.f};
    }

    #pragma unroll
    for (int ks2 = 0; ks2 < 2; ks2++) {
      bf16x8 bfr[4];
      #pragma unroll
      for (int nn = 0; nn < 4; nn++)
        bfr[nn] = ldbf8(&Bt[cur][(ncol + nn*16 + lr)*64 + (((ks2*4 + lg) ^ rsw) * 8)]);
      #pragma unroll
      for (int mt = 0; mt < 4; mt++)
        #pragma unroll
        for (int nn = 0; nn < 4; nn++)
          acc[mt][nn] = __builtin_amdgcn_mfma_f32_16x16x32_bf16(af[ks2][mt], bfr[nn], acc[mt][nn], 0, 0, 0);
    }

    if (u + 1 < 48) {                        // A prefetch (WAR after MFMAs read af)
      int un = u + 1;
      LOADA(un - (un / 12) * 12);
    }

    if (kt == 11) {
      #pragma unroll
      for (int mt = 0; mt < 4; mt++) {
        #pragma unroll
        for (int r = 0; r < 4; r++) {
          int cc = cc0 + mrow + mt*16 + lg*4 + r;
          float inv = invq[cc], beta = betaq[cc];
          int br = cc / C_, c = cc % C_;
          u8* dst = ((br == 0) ? qs : ((br == 1) ? ks_ : vs)) + (size_t)c * J_ + t * J1_ + colb;
          #pragma unroll
          for (int nn = 0; nn < 4; nn++) {
            int col = ncol + nn*16 + lr;
            float yb = __fadd_rn(__fmul_rn(acc[mt][nn][r], inv), beta);
            float v = vst[mt][nn][r];
            v = __fadd_rn(v, __fmul_rn(__fsub_rn(yb, v), 0.5f));
            bool sgl = (v >= 1.0f);
            vst[mt][nn][r] = __fmul_rn(v, sgl ? 0.f : 1.f);
            dst[col] = sgl ? (u8)1 : (u8)0;
          }
        }
      }
    }

    if (u < 47) {
      // counted wait: drains this step's 4 B-stage loads (oldest); the 8 A-loads
      // stay in flight across the barrier. Epilogue steps drain stores too.
      if (kt == 11) asm volatile("s_waitcnt vmcnt(0)" ::: "memory");
      else          asm volatile("s_waitcnt vmcnt(8)" ::: "memory");
      __builtin_amdgcn_s_barrier();
    }
  }
}

// ---------------------------------------------------------------- K3: attention (exact i8 MFMA) + attn_lif fused over T
// u32-transposed staging with chunk-XOR swizzle; swapped QK^T -> packed u32 arow writes.
__global__ __launch_bounds__(256) void k3_attn(
    const u8* __restrict__ qs, const u8* __restrict__ ks_, const u8* __restrict__ vs,
    u16* __restrict__ s2t)
{
  int b = blockIdx.x >> 3, h = blockIdx.x & 7;
  __shared__ __align__(16) signed char qL[208 * 80];   // [n][5 x 16B chunks, XOR-swizzled]
  __shared__ __align__(16) signed char kL[208 * 80];
  __shared__ __align__(16) signed char vL[48 * 272];
  __shared__ __align__(16) signed char aL[4 * 16 * 272];

  int tid = threadIdx.x, lane = tid & 63, w = tid >> 6;
  int lr = lane & 15, lg = lane >> 4;

  for (int i = tid; i < 208*80/4; i += 256) { ((int*)qL)[i] = 0; ((int*)kL)[i] = 0; }
  for (int i = tid; i < 48*272/4; i += 256) ((int*)vL)[i] = 0;
  for (int i = tid; i < 4*16*272/4; i += 256) ((int*)aL)[i] = 0;
  __syncthreads();

  float vst[4][3][4];
  #pragma unroll
  for (int a = 0; a < 4; a++)
    #pragma unroll
    for (int d = 0; d < 3; d++)
      #pragma unroll
      for (int r = 0; r < 4; r++) vst[a][d][r] = 0.f;

  signed char* arow = &aL[w * 16 * 272];
  const i32x4 zero4 = {0, 0, 0, 0};

  for (int t = 0; t < 4; t++) {
    size_t off = (size_t)(t*B_ + b) * N_;
    for (int i = tid; i < 588; i += 256) {
      int dd4 = i / 49, n4 = i - dd4 * 49;
      size_t rb = (size_t)(h*DH_ + dd4*4) * J_ + off + n4*4;
      u32 q0 = *(const u32*)(qs + rb);
      u32 q1 = *(const u32*)(qs + rb + J_);
      u32 q2 = *(const u32*)(qs + rb + 2*(size_t)J_);
      u32 q3 = *(const u32*)(qs + rb + 3*(size_t)J_);
      u32 k0 = *(const u32*)(ks_ + rb);
      u32 k1 = *(const u32*)(ks_ + rb + J_);
      u32 k2 = *(const u32*)(ks_ + rb + 2*(size_t)J_);
      u32 k3 = *(const u32*)(ks_ + rb + 3*(size_t)J_);
      u32 v0 = *(const u32*)(vs + rb);
      u32 v1 = *(const u32*)(vs + rb + J_);
      u32 v2 = *(const u32*)(vs + rb + 2*(size_t)J_);
      u32 v3 = *(const u32*)(vs + rb + 3*(size_t)J_);
      int c16 = dd4 >> 2, bb4 = (dd4 & 3) << 2;
      #pragma unroll
      for (int jj = 0; jj < 4; jj++) {
        u32 tq = ((q0 >> (8*jj)) & 0xFFu) | (((q1 >> (8*jj)) & 0xFFu) << 8)
               | (((q2 >> (8*jj)) & 0xFFu) << 16) | (((q3 >> (8*jj)) & 0xFFu) << 24);
        u32 tk = ((k0 >> (8*jj)) & 0xFFu) | (((k1 >> (8*jj)) & 0xFFu) << 8)
               | (((k2 >> (8*jj)) & 0xFFu) << 16) | (((k3 >> (8*jj)) & 0xFFu) << 24);
        int n = n4*4 + jj;
        int cs = ((c16 ^ SWZ(n)) << 4) + bb4;
        *(u32*)(qL + n*80 + cs) = tq;
        *(u32*)(kL + n*80 + cs) = tk;
      }
      *(u32*)(vL + (dd4*4 + 0)*272 + n4*4) = v0;
      *(u32*)(vL + (dd4*4 + 1)*272 + n4*4) = v1;
      *(u32*)(vL + (dd4*4 + 2)*272 + n4*4) = v2;
      *(u32*)(vL + (dd4*4 + 3)*272 + n4*4) = v3;
    }
    __syncthreads();

    int nslots = (w == 0) ? 4 : 3;
    for (int sl = 0; sl < nslots; sl++) {
      int ni = w + sl * 4;
      int nq = ni*16 + lr;
      i32x4 bq = *reinterpret_cast<const i32x4*>(qL + nq*80 + ((lg ^ SWZ(nq)) << 4));
      for (int mj = 0; mj < 13; mj++) {
        int mk = mj*16 + lr;
        i32x4 ak = *reinterpret_cast<const i32x4*>(kL + mk*80 + ((lg ^ SWZ(mk)) << 4));
        i32x4 d = __builtin_amdgcn_mfma_i32_16x16x64_i8(ak, bq, zero4, 0, 0, 0);
        u32 pk = (u32)d[0] | ((u32)d[1] << 8) | ((u32)d[2] << 16) | ((u32)d[3] << 24);
        *(u32*)(arow + lr*272 + mj*16 + lg*4) = pk;
      }
      #pragma unroll
      for (int di = 0; di < 3; di++) {
        i32x4 acc = zero4;
        #pragma unroll
        for (int ks2 = 0; ks2 < 4; ks2++) {
          i32x4 aa = *reinterpret_cast<const i32x4*>(arow + lr*272 + ks2*64 + lg*16);
          i32x4 bb = *reinterpret_cast<const i32x4*>(vL + (di*16 + lr)*272 + ks2*64 + lg*16);
          acc = __builtin_amdgcn_mfma_i32_16x16x64_i8(aa, bb, acc, 0, 0, 0);
        }
        #pragma unroll
        for (int r = 0; r < 4; r++) {
          int n = ni*16 + lg*4 + r;
          float xv = __fmul_rn((float)acc[r], 0.125f);
          float v = vst[sl][di][r];
          v = __fadd_rn(v, __fmul_rn(__fsub_rn(xv, v), 0.5f));
          bool s = (v >= 0.5f);
          vst[sl][di][r] = __fmul_rn(v, s ? 0.f : 1.f);
          if (n < N_)
            s2t[((size_t)((t*B_ + b)*N_ + n))*C_ + h*DH_ + di*16 + lr] = s ? (u16)0x3F80 : (u16)0;
        }
      }
    }
    __syncthreads();
  }
}

// ---------------------------------------------------------------- G2: proj GEMM (2-phase dbuf B + A-prefetch)
__global__ __launch_bounds__(256, 2) void g2_proj(
    const u16* __restrict__ A2pf, const u16* __restrict__ s2t,
    const float* __restrict__ invp, const float* __restrict__ betap,
    const float* __restrict__ pb, const float* __restrict__ x,
    float* __restrict__ out)
{
  int blk = blockIdx.x;
  int grp = blk / 24, rem = blk % 24;
  int bm = rem >> 3;
  int bn = grp * 8 + (rem & 7);
  int cc0 = bm * 128, j0 = bn * 128;

  __shared__ u16 Bt[2][128 * 64];

  int tid = threadIdx.x;
  int lane = tid & 63, w = tid >> 6;
  int lr = lane & 15, lg = lane >> 4;
  int rsw = lr & 7;
  int wm = w & 1;
  int mrow = wm * 64, ncol = (w >> 1) * 64;

  f32x4 acc[4][4];
  #pragma unroll
  for (int a = 0; a < 4; a++)
    #pragma unroll
    for (int bq = 0; bq < 4; bq++) acc[a][bq] = (f32x4){0.f, 0.f, 0.f, 0.f};

  bf16x8 af[2][4];

  auto STAGE = [&](int bi, int kt2) {
    int ck0 = kt2 * 64;
    int ckB = (ck0 >= C_) ? (ck0 - C_) : ck0;
    #pragma unroll
    for (int i = 0; i < 4; i++) {
      int L0 = tid + i * 256;
      int r = L0 >> 3;
      int c = (L0 & 7) ^ (r & 7);
      gload16(s2t + (size_t)(j0 + r) * C_ + ckB + c * 8, &Bt[bi][L0 * 8]);
    }
  };
  auto LOADA = [&](int kt2) {
    int wb = (bm * 12 + kt2) * 2 + wm;
    #pragma unroll
    for (int ks2 = 0; ks2 < 2; ks2++)
      #pragma unroll
      for (int mt = 0; mt < 4; mt++)
        af[ks2][mt] = ldbf8(A2pf + ((size_t)(((wb * 4 + mt) * 2 + ks2) * 64) + lane) * 8);
  };

  STAGE(0, 0);
  LOADA(0);
  asm volatile("s_waitcnt vmcnt(0)" ::: "memory");
  __builtin_amdgcn_s_barrier();

  for (int kt = 0; kt < 12; kt++) {
    int cur = kt & 1;
    if (kt + 1 < 12) STAGE(cur ^ 1, kt + 1);

    #pragma unroll
    for (int ks2 = 0; ks2 < 2; ks2++) {
      bf16x8 bfr[4];
      #pragma unroll
      for (int nn = 0; nn < 4; nn++)
        bfr[nn] = ldbf8(&Bt[cur][(ncol + nn*16 + lr)*64 + (((ks2*4 + lg) ^ rsw) * 8)]);
      #pragma unroll
      for (int mt = 0; mt < 4; mt++)
        #pragma unroll
        for (int nn = 0; nn < 4; nn++)
          acc[mt][nn] = __builtin_amdgcn_mfma_f32_16x16x32_bf16(af[ks2][mt], bfr[nn], acc[mt][nn], 0, 0, 0);
    }

    if (kt + 1 < 12) {
      LOADA(kt + 1);
      asm volatile("s_waitcnt vmcnt(8)" ::: "memory");
      __builtin_amdgcn_s_barrier();
    }
  }

  #pragma unroll
  for (int mt = 0; mt < 4; mt++) {
    #pragma unroll
    for (int r = 0; r < 4; r++) {
      int cc = cc0 + mrow + mt*16 + lg*4 + r;
      float inv = invp[cc], beta = betap[cc], pbv = pb[cc];
      #pragma unroll
      for (int nn = 0; nn < 4; nn++) {
        int j = j0 + ncol + nn*16 + lr;
        float y = __fadd_rn(acc[mt][nn][r], pbv);
        float o = __fadd_rn(__fmul_rn(y, inv), beta);
        int jq = j / N_, n = j % N_;
        size_t addr = ((size_t)jq * C_ + cc) * N_ + n;
        out[addr] = __fadd_rn(o, x[addr]);
      }
    }
  }
}

// ---------------------------------------------------------------- launch
extern "C" void kernel_launch(void* const* d_in, const int* in_sizes, int n_in,
                              void* d_out, int out_size, void* d_ws, size_t ws_size,
                              hipStream_t stream)
{
  (void)in_sizes; (void)n_in; (void)out_size; (void)ws_size;
  const float* x   = (const float*)d_in[0];
  const float* qw  = (const float*)d_in[1];
  const float* kw  = (const float*)d_in[2];
  const float* vw  = (const float*)d_in[3];
  const float* pw  = (const float*)d_in[4];
  const float* pbv = (const float*)d_in[5];
  const float* qbn = (const float*)d_in[6];
  const float* kbn = (const float*)d_in[7];
  const float* vbn = (const float*)d_in[8];
  const float* pbn = (const float*)d_in[9];

  char* ws = (char*)d_ws;
  u16*   A2f   = (u16*)  (ws + 0);         // 1152*768*2   = 1769472
  u16*   A2pf  = (u16*)  (ws + 1769472);   // 384*768*2    = 589824
  float* invq  = (float*)(ws + 2359296);
  float* betaq = (float*)(ws + 2363904);
  float* invp  = (float*)(ws + 2368512);
  float* betap = (float*)(ws + 2370048);
  u16*   xs_t  = (u16*)  (ws + 2371584);   // 50176*384*2  = 38535168
  u16*   s2t   = xs_t;                     // aliased: consumed by G1 before K3 writes
  u8*    qs    = (u8*)   (ws + 40906752);  // 384*50176    = 19267584
  u8*    ks    = (u8*)   (ws + 60174336);
  u8*    vs    = (u8*)   (ws + 79441920);  // end = 98709504 bytes

  k0_prep<<<4614, 256, 0, stream>>>(qw, kw, vw, pw, qbn, kbn, vbn, pbn,
                                    A2f, A2pf, invq, betaq, invp, betap);
  k1_lif_x<<<768, 256, 0, stream>>>(x, xs_t);
  g1_branch<<<936, 256, 0, stream>>>(A2f, xs_t, invq, betaq, qs, ks, vs);
  k3_attn<<<512, 256, 0, stream>>>(qs, ks, vs, s2t);
  g2_proj<<<1176, 256, 0, stream>>>(A2pf, s2t, invp, betap, pbv, x, (float*)d_out);
}

// Round 12
// 293.635 us; speedup vs baseline: 1.0301x; 1.0301x over previous
//
#include <hip/hip_runtime.h>
#include <hip/hip_bf16.h>

typedef unsigned short u16;
typedef unsigned char  u8;
typedef unsigned int   u32;
typedef unsigned long long u64;
typedef __attribute__((ext_vector_type(8))) short  short8;
typedef __attribute__((ext_vector_type(8))) __bf16 bf16x8;
typedef __attribute__((ext_vector_type(4))) float  f32x4;
typedef __attribute__((ext_vector_type(4))) int    i32x4;

#define DI static __device__ __forceinline__

constexpr int T_ = 4, B_ = 64, C_ = 384, N_ = 196, NH_ = 8, DH_ = 48;
constexpr int J1_ = B_ * N_;           // 12544 columns per t-slice (= 98*128)
constexpr int J_  = T_ * J1_;          // 50176 flat columns
constexpr int K2_ = 2 * C_;            // 768 (hi|lo split-K)
constexpr int M1_ = 3 * C_;            // 1152 (q|k|v output channels)

DI u16 f2bf(float x){ __hip_bfloat16 h = __float2bfloat16(x); u16 u; __builtin_memcpy(&u,&h,2); return u; }
DI float bf2f(u16 u){ __hip_bfloat16 h; __builtin_memcpy(&h,&u,2); return __bfloat162float(h); }

DI void gload16(const void* g, void* lds){
  __builtin_amdgcn_global_load_lds((const __attribute__((address_space(1))) u32*)g,
                                   (__attribute__((address_space(3))) u32*)lds, 16, 0, 0);
}
DI bf16x8 ldbf8(const u16* p){ short8 v = *(const short8*)p; return __builtin_bit_cast(bf16x8, v); }
DI int SWZ(int n){ return ((n >> 3) ^ (n >> 5)) & 3; }

// ---------------------------------------------------------------- K0: prep
// Weights in fragment-major coalesced layout (one 16B/lane load per fragment):
// A2f[bm][kt][wm][mt][ks2][lane][8]; cc = bm*128+wm*64+mt*16+(lane&15);
// k = kt*64+ks2*32+(lane>>4)*8+e (k<384: bf16 hi; else exact lo residual).
__global__ __launch_bounds__(256) void k0_prep(
    const float* __restrict__ qw, const float* __restrict__ kw,
    const float* __restrict__ vw, const float* __restrict__ pw,
    const float* __restrict__ qbn, const float* __restrict__ kbn,
    const float* __restrict__ vbn, const float* __restrict__ pbn,
    u16* __restrict__ A2f, u16* __restrict__ A2pf,
    float* __restrict__ invq, float* __restrict__ betaq,
    float* __restrict__ invp, float* __restrict__ betap)
{
  int id = blockIdx.x * 256 + threadIdx.x;
  const int nAf = M1_ * K2_;   // 884736
  const int nPf = C_ * K2_;    // 294912
  if (id < nAf) {
    int tmp = id;
    int e    = tmp & 7;  tmp >>= 3;
    int lane = tmp & 63; tmp >>= 6;
    int ks2  = tmp & 1;  tmp >>= 1;
    int mt   = tmp & 3;  tmp >>= 2;
    int wm   = tmp & 1;  tmp >>= 1;
    int kt   = tmp % 12;
    int bm   = tmp / 12;
    int cc = bm*128 + wm*64 + mt*16 + (lane & 15);
    int k  = kt*64 + ks2*32 + (lane >> 4)*8 + e;
    int br = cc / C_, row = cc % C_;
    const float* w = (br == 0) ? qw : ((br == 1) ? kw : vw);
    float wv = w[row * C_ + (k < C_ ? k : k - C_)];
    u16 hi = f2bf(wv);
    A2f[id] = (k < C_) ? hi : f2bf(__fsub_rn(wv, bf2f(hi)));
  } else if (id < nAf + nPf) {
    int tmp = id - nAf;
    int id2 = tmp;
    int e    = tmp & 7;  tmp >>= 3;
    int lane = tmp & 63; tmp >>= 6;
    int ks2  = tmp & 1;  tmp >>= 1;
    int mt   = tmp & 3;  tmp >>= 2;
    int wm   = tmp & 1;  tmp >>= 1;
    int kt   = tmp % 12;
    int bm   = tmp / 12;
    int cc = bm*128 + wm*64 + mt*16 + (lane & 15);
    int k  = kt*64 + ks2*32 + (lane >> 4)*8 + e;
    float wv = pw[cc * C_ + (k < C_ ? k : k - C_)];
    u16 hi = f2bf(wv);
    A2pf[id2] = (k < C_) ? hi : f2bf(__fsub_rn(wv, bf2f(hi)));
  } else if (id < nAf + nPf + M1_) {
    int c = id - nAf - nPf;
    int br = c / C_, cr = c % C_;
    const float* p = (br == 0) ? qbn : ((br == 1) ? kbn : vbn);
    float g = p[cr], bb = p[C_ + cr], mm = p[2*C_ + cr], vv = p[3*C_ + cr];
    float inv = g / sqrtf(__fadd_rn(vv, 1e-5f));
    invq[c] = inv; betaq[c] = __fsub_rn(bb, __fmul_rn(mm, inv));
  } else if (id < nAf + nPf + M1_ + C_) {
    int c = id - nAf - nPf - M1_;
    float g = pbn[c], bb = pbn[C_ + c], mm = pbn[2*C_ + c], vv = pbn[3*C_ + c];
    float inv = g / sqrtf(__fadd_rn(vv, 1e-5f));
    invp[c] = inv; betap[c] = __fsub_rn(bb, __fmul_rn(mm, inv));
  }
}

// ---------------------------------------------------------------- K1: LIF(x) -> xs_t[j][c], float4-vectorized
__global__ __launch_bounds__(256) void k1_lif_x(const float* __restrict__ x, u16* __restrict__ xs_t)
{
  int b = blockIdx.x / 12, ch = blockIdx.x % 12;
  int c0 = ch * 32;
  __shared__ u16 sp[4 * 32 * 200];          // stride 200 keeps u64 writes 8B-aligned
  int tid = threadIdx.x;
  for (int idx = tid; idx < 32 * 49; idx += 256) {
    int ci = idx / 49, n4 = idx % 49;
    float v0 = 0.f, v1 = 0.f, v2 = 0.f, v3 = 0.f;
    for (int t = 0; t < 4; t++) {
      const float4 xv = *reinterpret_cast<const float4*>(
          &x[((size_t)((t*B_ + b)*C_ + c0 + ci))*N_ + n4*4]);
      u16 s0, s1, s2, s3;
      v0 = __fadd_rn(v0, __fmul_rn(__fsub_rn(xv.x, v0), 0.5f)); { bool s = (v0 >= 1.0f); s0 = s ? (u16)0x3F80 : (u16)0; v0 = __fmul_rn(v0, s ? 0.f : 1.f); }
      v1 = __fadd_rn(v1, __fmul_rn(__fsub_rn(xv.y, v1), 0.5f)); { bool s = (v1 >= 1.0f); s1 = s ? (u16)0x3F80 : (u16)0; v1 = __fmul_rn(v1, s ? 0.f : 1.f); }
      v2 = __fadd_rn(v2, __fmul_rn(__fsub_rn(xv.z, v2), 0.5f)); { bool s = (v2 >= 1.0f); s2 = s ? (u16)0x3F80 : (u16)0; v2 = __fmul_rn(v2, s ? 0.f : 1.f); }
      v3 = __fadd_rn(v3, __fmul_rn(__fsub_rn(xv.w, v3), 0.5f)); { bool s = (v3 >= 1.0f); s3 = s ? (u16)0x3F80 : (u16)0; v3 = __fmul_rn(v3, s ? 0.f : 1.f); }
      u64 pk = (u64)s0 | ((u64)s1 << 16) | ((u64)s2 << 32) | ((u64)s3 << 48);
      *reinterpret_cast<u64*>(&sp[(t*32 + ci)*200 + n4*4]) = pk;
    }
  }
  __syncthreads();
  for (int idx = tid; idx < 4 * 8 * N_; idx += 256) {   // 6272: u64 over 4 consecutive c
    int ci4 = idx & 7; int q = idx >> 3; int n = q % N_; int t = q / N_;
    u16 a0 = sp[(t*32 + ci4*4 + 0)*200 + n];
    u16 a1 = sp[(t*32 + ci4*4 + 1)*200 + n];
    u16 a2 = sp[(t*32 + ci4*4 + 2)*200 + n];
    u16 a3 = sp[(t*32 + ci4*4 + 3)*200 + n];
    u64 pk = (u64)a0 | ((u64)a1 << 16) | ((u64)a2 << 32) | ((u64)a3 << 48);
    *reinterpret_cast<u64*>(&xs_t[((size_t)((t*B_ + b)*N_ + n))*C_ + c0 + ci4*4]) = pk;
  }
}

// ---------------------------------------------------------------- G1: branch GEMM (round-9 proven structure)
// m97 2-barrier structure; B-only LDS (16 KB, 4 gload16/thread); A fragments
// from L2-hot fragment-major table, prefetched one K-step ahead (WAR-ordered
// after the MFMA cluster) so their L2 latency never sits on the critical path.
__global__ __launch_bounds__(256, 2) void g1_branch(
    const u16* __restrict__ A2f, const u16* __restrict__ xs_t,
    const float* __restrict__ invq, const float* __restrict__ betaq,
    u8* __restrict__ qs, u8* __restrict__ ks_, u8* __restrict__ vs)
{
  int blk = blockIdx.x;
  int grp = blk / 72, rem = blk % 72;
  int bm = rem >> 3;
  int jt = grp * 8 + (rem & 7);
  if (jt >= 98) return;
  int cc0 = bm * 128;
  int colb = jt * 128;

  __shared__ u16 Bt[128 * 64];

  int tid = threadIdx.x;
  int lane = tid & 63, w = tid >> 6;
  int lr = lane & 15, lg = lane >> 4;
  int rsw = lr & 7;
  int wm = w & 1;
  int mrow = wm * 64, ncol = (w >> 1) * 64;

  float vst[4][4][4];
  #pragma unroll
  for (int a = 0; a < 4; a++)
    #pragma unroll
    for (int bq = 0; bq < 4; bq++)
      #pragma unroll
      for (int r = 0; r < 4; r++) vst[a][bq][r] = 0.f;

  f32x4 acc[4][4];
  bf16x8 af[2][4];

  auto LOADA = [&](int kt2) {
    int wb = (bm * 12 + kt2) * 2 + wm;
    #pragma unroll
    for (int ks2 = 0; ks2 < 2; ks2++)
      #pragma unroll
      for (int mt = 0; mt < 4; mt++)
        af[ks2][mt] = ldbf8(A2f + ((size_t)(((wb * 4 + mt) * 2 + ks2) * 64) + lane) * 8);
  };

  LOADA(0);   // prefetch for step 0

  for (int u = 0; u < 48; u++) {
    int t = u / 12, kt = u - t * 12;
    int ckB0 = kt * 64;
    int ckB = (ckB0 >= C_) ? (ckB0 - C_) : ckB0;
    long j0 = (long)t * J1_ + colb;

    // stage B only: 128x64 bf16 = 16 KB, 4 gload16 per thread
    #pragma unroll
    for (int i = 0; i < 4; i++) {
      int L0 = tid + i * 256;            // 0..1023
      int r = L0 >> 3;
      int c = (L0 & 7) ^ (r & 7);        // inverse-swizzled source chunk
      gload16(xs_t + (size_t)(j0 + r) * C_ + ckB + c * 8, &Bt[L0 * 8]);
    }

    if (kt == 0) {
      #pragma unroll
      for (int a = 0; a < 4; a++)
        #pragma unroll
        for (int bq = 0; bq < 4; bq++) acc[a][bq] = (f32x4){0.f, 0.f, 0.f, 0.f};
    }
    __syncthreads();

    #pragma unroll
    for (int ks2 = 0; ks2 < 2; ks2++) {
      bf16x8 bfr[4];
      #pragma unroll
      for (int nn = 0; nn < 4; nn++)
        bfr[nn] = ldbf8(&Bt[(ncol + nn*16 + lr)*64 + (((ks2*4 + lg) ^ rsw) * 8)]);
      #pragma unroll
      for (int mt = 0; mt < 4; mt++)
        #pragma unroll
        for (int nn = 0; nn < 4; nn++)
          acc[mt][nn] = __builtin_amdgcn_mfma_f32_16x16x32_bf16(af[ks2][mt], bfr[nn], acc[mt][nn], 0, 0, 0);
    }

    // prefetch A for next step (WAR: compiler must order these after the MFMAs read af)
    if (u + 1 < 48) {
      int un = u + 1;
      LOADA(un - (un / 12) * 12);
    }

    if (kt == 11) {
      #pragma unroll
      for (int mt = 0; mt < 4; mt++) {
        #pragma unroll
        for (int r = 0; r < 4; r++) {
          int cc = cc0 + mrow + mt*16 + lg*4 + r;
          float inv = invq[cc], beta = betaq[cc];
          int br = cc / C_, c = cc % C_;
          u8* dst = ((br == 0) ? qs : ((br == 1) ? ks_ : vs)) + (size_t)c * J_ + t * J1_ + colb;
          #pragma unroll
          for (int nn = 0; nn < 4; nn++) {
            int col = ncol + nn*16 + lr;
            float yb = __fadd_rn(__fmul_rn(acc[mt][nn][r], inv), beta);
            float v = vst[mt][nn][r];
            v = __fadd_rn(v, __fmul_rn(__fsub_rn(yb, v), 0.5f));
            bool sgl = (v >= 1.0f);
            vst[mt][nn][r] = __fmul_rn(v, sgl ? 0.f : 1.f);
            dst[col] = sgl ? (u8)1 : (u8)0;
          }
        }
      }
    }
    __syncthreads();
  }
}

// ---------------------------------------------------------------- K3: attention (exact i8 MFMA) + attn_lif fused over T
// u32-transposed staging with chunk-XOR swizzle; swapped QK^T -> packed u32 arow writes.
__global__ __launch_bounds__(256) void k3_attn(
    const u8* __restrict__ qs, const u8* __restrict__ ks_, const u8* __restrict__ vs,
    u16* __restrict__ s2t)
{
  int b = blockIdx.x >> 3, h = blockIdx.x & 7;
  __shared__ __align__(16) signed char qL[208 * 80];   // [n][5 x 16B chunks, XOR-swizzled]
  __shared__ __align__(16) signed char kL[208 * 80];
  __shared__ __align__(16) signed char vL[48 * 272];
  __shared__ __align__(16) signed char aL[4 * 16 * 272];

  int tid = threadIdx.x, lane = tid & 63, w = tid >> 6;
  int lr = lane & 15, lg = lane >> 4;

  for (int i = tid; i < 208*80/4; i += 256) { ((int*)qL)[i] = 0; ((int*)kL)[i] = 0; }
  for (int i = tid; i < 48*272/4; i += 256) ((int*)vL)[i] = 0;
  for (int i = tid; i < 4*16*272/4; i += 256) ((int*)aL)[i] = 0;
  __syncthreads();

  float vst[4][3][4];
  #pragma unroll
  for (int a = 0; a < 4; a++)
    #pragma unroll
    for (int d = 0; d < 3; d++)
      #pragma unroll
      for (int r = 0; r < 4; r++) vst[a][d][r] = 0.f;

  signed char* arow = &aL[w * 16 * 272];
  const i32x4 zero4 = {0, 0, 0, 0};

  for (int t = 0; t < 4; t++) {
    size_t off = (size_t)(t*B_ + b) * N_;
    for (int i = tid; i < 588; i += 256) {
      int dd4 = i / 49, n4 = i - dd4 * 49;
      size_t rb = (size_t)(h*DH_ + dd4*4) * J_ + off + n4*4;
      u32 q0 = *(const u32*)(qs + rb);
      u32 q1 = *(const u32*)(qs + rb + J_);
      u32 q2 = *(const u32*)(qs + rb + 2*(size_t)J_);
      u32 q3 = *(const u32*)(qs + rb + 3*(size_t)J_);
      u32 k0 = *(const u32*)(ks_ + rb);
      u32 k1 = *(const u32*)(ks_ + rb + J_);
      u32 k2 = *(const u32*)(ks_ + rb + 2*(size_t)J_);
      u32 k3 = *(const u32*)(ks_ + rb + 3*(size_t)J_);
      u32 v0 = *(const u32*)(vs + rb);
      u32 v1 = *(const u32*)(vs + rb + J_);
      u32 v2 = *(const u32*)(vs + rb + 2*(size_t)J_);
      u32 v3 = *(const u32*)(vs + rb + 3*(size_t)J_);
      int c16 = dd4 >> 2, bb4 = (dd4 & 3) << 2;
      #pragma unroll
      for (int jj = 0; jj < 4; jj++) {
        u32 tq = ((q0 >> (8*jj)) & 0xFFu) | (((q1 >> (8*jj)) & 0xFFu) << 8)
               | (((q2 >> (8*jj)) & 0xFFu) << 16) | (((q3 >> (8*jj)) & 0xFFu) << 24);
        u32 tk = ((k0 >> (8*jj)) & 0xFFu) | (((k1 >> (8*jj)) & 0xFFu) << 8)
               | (((k2 >> (8*jj)) & 0xFFu) << 16) | (((k3 >> (8*jj)) & 0xFFu) << 24);
        int n = n4*4 + jj;
        int cs = ((c16 ^ SWZ(n)) << 4) + bb4;
        *(u32*)(qL + n*80 + cs) = tq;
        *(u32*)(kL + n*80 + cs) = tk;
      }
      *(u32*)(vL + (dd4*4 + 0)*272 + n4*4) = v0;
      *(u32*)(vL + (dd4*4 + 1)*272 + n4*4) = v1;
      *(u32*)(vL + (dd4*4 + 2)*272 + n4*4) = v2;
      *(u32*)(vL + (dd4*4 + 3)*272 + n4*4) = v3;
    }
    __syncthreads();

    int nslots = (w == 0) ? 4 : 3;
    for (int sl = 0; sl < nslots; sl++) {
      int ni = w + sl * 4;
      int nq = ni*16 + lr;
      i32x4 bq = *reinterpret_cast<const i32x4*>(qL + nq*80 + ((lg ^ SWZ(nq)) << 4));
      for (int mj = 0; mj < 13; mj++) {
        int mk = mj*16 + lr;
        i32x4 ak = *reinterpret_cast<const i32x4*>(kL + mk*80 + ((lg ^ SWZ(mk)) << 4));
        i32x4 d = __builtin_amdgcn_mfma_i32_16x16x64_i8(ak, bq, zero4, 0, 0, 0);
        u32 pk = (u32)d[0] | ((u32)d[1] << 8) | ((u32)d[2] << 16) | ((u32)d[3] << 24);
        *(u32*)(arow + lr*272 + mj*16 + lg*4) = pk;
      }
      #pragma unroll
      for (int di = 0; di < 3; di++) {
        i32x4 acc = zero4;
        #pragma unroll
        for (int ks2 = 0; ks2 < 4; ks2++) {
          i32x4 aa = *reinterpret_cast<const i32x4*>(arow + lr*272 + ks2*64 + lg*16);
          i32x4 bb = *reinterpret_cast<const i32x4*>(vL + (di*16 + lr)*272 + ks2*64 + lg*16);
          acc = __builtin_amdgcn_mfma_i32_16x16x64_i8(aa, bb, acc, 0, 0, 0);
        }
        #pragma unroll
        for (int r = 0; r < 4; r++) {
          int n = ni*16 + lg*4 + r;
          float xv = __fmul_rn((float)acc[r], 0.125f);
          float v = vst[sl][di][r];
          v = __fadd_rn(v, __fmul_rn(__fsub_rn(xv, v), 0.5f));
          bool s = (v >= 0.5f);
          vst[sl][di][r] = __fmul_rn(v, s ? 0.f : 1.f);
          if (n < N_)
            s2t[((size_t)((t*B_ + b)*N_ + n))*C_ + h*DH_ + di*16 + lr] = s ? (u16)0x3F80 : (u16)0;
        }
      }
    }
    __syncthreads();
  }
}

// ---------------------------------------------------------------- G2: proj GEMM (round-9 proven structure)
__global__ __launch_bounds__(256, 2) void g2_proj(
    const u16* __restrict__ A2pf, const u16* __restrict__ s2t,
    const float* __restrict__ invp, const float* __restrict__ betap,
    const float* __restrict__ pb, const float* __restrict__ x,
    float* __restrict__ out)
{
  int blk = blockIdx.x;
  int grp = blk / 24, rem = blk % 24;
  int bm = rem >> 3;
  int bn = grp * 8 + (rem & 7);
  int cc0 = bm * 128, j0 = bn * 128;

  __shared__ u16 Bt[128 * 64];

  int tid = threadIdx.x;
  int lane = tid & 63, w = tid >> 6;
  int lr = lane & 15, lg = lane >> 4;
  int rsw = lr & 7;
  int wm = w & 1;
  int mrow = wm * 64, ncol = (w >> 1) * 64;

  f32x4 acc[4][4];
  #pragma unroll
  for (int a = 0; a < 4; a++)
    #pragma unroll
    for (int bq = 0; bq < 4; bq++) acc[a][bq] = (f32x4){0.f, 0.f, 0.f, 0.f};

  bf16x8 af[2][4];
  auto LOADA = [&](int kt2) {
    int wb = (bm * 12 + kt2) * 2 + wm;
    #pragma unroll
    for (int ks2 = 0; ks2 < 2; ks2++)
      #pragma unroll
      for (int mt = 0; mt < 4; mt++)
        af[ks2][mt] = ldbf8(A2pf + ((size_t)(((wb * 4 + mt) * 2 + ks2) * 64) + lane) * 8);
  };

  LOADA(0);

  for (int kt = 0; kt < 12; kt++) {
    int ckB0 = kt * 64;
    int ckB = (ckB0 >= C_) ? (ckB0 - C_) : ckB0;
    #pragma unroll
    for (int i = 0; i < 4; i++) {
      int L0 = tid + i * 256;
      int r = L0 >> 3;
      int c = (L0 & 7) ^ (r & 7);
      gload16(s2t + (size_t)(j0 + r) * C_ + ckB + c * 8, &Bt[L0 * 8]);
    }
    __syncthreads();

    #pragma unroll
    for (int ks2 = 0; ks2 < 2; ks2++) {
      bf16x8 bfr[4];
      #pragma unroll
      for (int nn = 0; nn < 4; nn++)
        bfr[nn] = ldbf8(&Bt[(ncol + nn*16 + lr)*64 + (((ks2*4 + lg) ^ rsw) * 8)]);
      #pragma unroll
      for (int mt = 0; mt < 4; mt++)
        #pragma unroll
        for (int nn = 0; nn < 4; nn++)
          acc[mt][nn] = __builtin_amdgcn_mfma_f32_16x16x32_bf16(af[ks2][mt], bfr[nn], acc[mt][nn], 0, 0, 0);
    }

    if (kt < 11) LOADA(kt + 1);   // WAR-ordered prefetch
    __syncthreads();
  }

  #pragma unroll
  for (int mt = 0; mt < 4; mt++) {
    #pragma unroll
    for (int r = 0; r < 4; r++) {
      int cc = cc0 + mrow + mt*16 + lg*4 + r;
      float inv = invp[cc], beta = betap[cc], pbv = pb[cc];
      #pragma unroll
      for (int nn = 0; nn < 4; nn++) {
        int j = j0 + ncol + nn*16 + lr;
        float y = __fadd_rn(acc[mt][nn][r], pbv);
        float o = __fadd_rn(__fmul_rn(y, inv), beta);
        int jq = j / N_, n = j % N_;
        size_t addr = ((size_t)jq * C_ + cc) * N_ + n;
        out[addr] = __fadd_rn(o, x[addr]);
      }
    }
  }
}

// ---------------------------------------------------------------- launch
extern "C" void kernel_launch(void* const* d_in, const int* in_sizes, int n_in,
                              void* d_out, int out_size, void* d_ws, size_t ws_size,
                              hipStream_t stream)
{
  (void)in_sizes; (void)n_in; (void)out_size; (void)ws_size;
  const float* x   = (const float*)d_in[0];
  const float* qw  = (const float*)d_in[1];
  const float* kw  = (const float*)d_in[2];
  const float* vw  = (const float*)d_in[3];
  const float* pw  = (const float*)d_in[4];
  const float* pbv = (const float*)d_in[5];
  const float* qbn = (const float*)d_in[6];
  const float* kbn = (const float*)d_in[7];
  const float* vbn = (const float*)d_in[8];
  const float* pbn = (const float*)d_in[9];

  char* ws = (char*)d_ws;
  u16*   A2f   = (u16*)  (ws + 0);         // 1152*768*2   = 1769472
  u16*   A2pf  = (u16*)  (ws + 1769472);   // 384*768*2    = 589824
  float* invq  = (float*)(ws + 2359296);
  float* betaq = (float*)(ws + 2363904);
  float* invp  = (float*)(ws + 2368512);
  float* betap = (float*)(ws + 2370048);
  u16*   xs_t  = (u16*)  (ws + 2371584);   // 50176*384*2  = 38535168
  u16*   s2t   = xs_t;                     // aliased: consumed by G1 before K3 writes
  u8*    qs    = (u8*)   (ws + 40906752);  // 384*50176    = 19267584
  u8*    ks    = (u8*)   (ws + 60174336);
  u8*    vs    = (u8*)   (ws + 79441920);  // end = 98709504 bytes

  k0_prep<<<4614, 256, 0, stream>>>(qw, kw, vw, pw, qbn, kbn, vbn, pbn,
                                    A2f, A2pf, invq, betaq, invp, betap);
  k1_lif_x<<<768, 256, 0, stream>>>(x, xs_t);
  g1_branch<<<936, 256, 0, stream>>>(A2f, xs_t, invq, betaq, qs, ks, vs);
  k3_attn<<<512, 256, 0, stream>>>(qs, ks, vs, s2t);
  g2_proj<<<1176, 256, 0, stream>>>(A2pf, s2t, invp, betap, pbv, x, (float*)d_out);
}